// Round 1
// baseline (615.030 us; speedup 1.0000x reference)
//
#include <hip/hip_runtime.h>
#include <hip/hip_bf16.h>
#include <math.h>

typedef __attribute__((ext_vector_type(8))) short short8;
typedef __attribute__((ext_vector_type(4))) float f32x4;
typedef unsigned short ushort_t;

__device__ __forceinline__ ushort_t f2bf(float f) {
    union { float f; unsigned u; } v; v.f = f;
    unsigned r = v.u + 0x7FFF + ((v.u >> 16) & 1);
    return (ushort_t)(r >> 16);
}
__device__ __forceinline__ float bf2f(short s) {
    union { unsigned u; float f; } v; v.u = ((unsigned)(ushort_t)s) << 16;
    return v.f;
}

// ---------------- fp32 -> bf16 convert (vectorized x8) ----------------
__global__ void cvt_kernel(const float* __restrict__ src, ushort_t* __restrict__ dst, int n8) {
    int i = blockIdx.x * blockDim.x + threadIdx.x;
    int stride = gridDim.x * blockDim.x;
    for (; i < n8; i += stride) {
        const float4* s = reinterpret_cast<const float4*>(src) + (size_t)i * 2;
        float4 a = s[0], b = s[1];
        short8 o;
        o[0] = (short)f2bf(a.x); o[1] = (short)f2bf(a.y);
        o[2] = (short)f2bf(a.z); o[3] = (short)f2bf(a.w);
        o[4] = (short)f2bf(b.x); o[5] = (short)f2bf(b.y);
        o[6] = (short)f2bf(b.z); o[7] = (short)f2bf(b.w);
        reinterpret_cast<short8*>(dst)[i] = o;
    }
}

// ---------------- GEMM NT: C[m,n] = sum_k A[m,k]*W[n,k] (bf16 in, bf16/f32 out) ----------------
// 128x128 tile, BK=32, 256 threads = 4 waves (2x2), each wave 64x64 = 4x4 frags of 16x16x32.
template<int OUT_BF16>
__global__ __launch_bounds__(256) void gemm_nt(const ushort_t* __restrict__ A,
                                               const ushort_t* __restrict__ Bw,
                                               void* __restrict__ Cout,
                                               int M, int N, int K) {
    __shared__ ushort_t As[128][40];
    __shared__ ushort_t Bs[128][40];
    const int t = threadIdx.x;
    const int wid = t >> 6, lane = t & 63;
    const int wm = wid >> 1, wn = wid & 1;
    const int lr = lane & 15, lg = lane >> 4;
    const int m0 = blockIdx.y * 128, n0 = blockIdx.x * 128;

    f32x4 acc[4][4] = {};

    const int tr = t >> 1;           // 0..127 staging row
    const int tc = (t & 1) * 16;     // 0 or 16
    const long rowA = (long)(m0 + tr) * K + tc;
    const long rowB = (long)(n0 + tr) * K + tc;

    for (int k0 = 0; k0 < K; k0 += 32) {
        __syncthreads();
        *reinterpret_cast<short8*>(&As[tr][tc])     = *reinterpret_cast<const short8*>(A + rowA + k0);
        *reinterpret_cast<short8*>(&As[tr][tc + 8]) = *reinterpret_cast<const short8*>(A + rowA + k0 + 8);
        *reinterpret_cast<short8*>(&Bs[tr][tc])     = *reinterpret_cast<const short8*>(Bw + rowB + k0);
        *reinterpret_cast<short8*>(&Bs[tr][tc + 8]) = *reinterpret_cast<const short8*>(Bw + rowB + k0 + 8);
        __syncthreads();
        short8 af[4], bfr[4];
        #pragma unroll
        for (int m = 0; m < 4; ++m)
            af[m] = *reinterpret_cast<const short8*>(&As[wm * 64 + m * 16 + lr][lg * 8]);
        #pragma unroll
        for (int n = 0; n < 4; ++n)
            bfr[n] = *reinterpret_cast<const short8*>(&Bs[wn * 64 + n * 16 + lr][lg * 8]);
        #pragma unroll
        for (int m = 0; m < 4; ++m)
            #pragma unroll
            for (int n = 0; n < 4; ++n)
                acc[m][n] = __builtin_amdgcn_mfma_f32_16x16x32_bf16(af[m], bfr[n], acc[m][n], 0, 0, 0);
    }
    // epilogue: C/D layout col = lane&15, row = (lane>>4)*4 + r  [m89-verified]
    #pragma unroll
    for (int m = 0; m < 4; ++m) {
        #pragma unroll
        for (int n = 0; n < 4; ++n) {
            #pragma unroll
            for (int r = 0; r < 4; ++r) {
                int row = m0 + wm * 64 + m * 16 + lg * 4 + r;
                int col = n0 + wn * 64 + n * 16 + lr;
                float v = acc[m][n][r];
                if (OUT_BF16)
                    ((ushort_t*)Cout)[(long)row * N + col] = f2bf(v);
                else
                    ((float*)Cout)[(long)row * N + col] = v;
            }
        }
    }
}

// ---------------- RoPE (interleaved pairs), in-place on (B,S,H,128) bf16 ----------------
__global__ void rope_kernel(ushort_t* __restrict__ X, const float* __restrict__ fc,
                            const float* __restrict__ fs, int total8, int H, int S) {
    int i = blockIdx.x * blockDim.x + threadIdx.x;
    if (i >= total8) return;
    const long base = (long)i * 8;
    const int d = (int)(base & 127);        // 0..120 step 8 (within head dim)
    const long row = base >> 7;             // (b*S + s)*H + h
    const int s_idx = (int)((row / H) % S);
    short8 v = *reinterpret_cast<const short8*>(X + base);
    short8 o;
    const int i0 = d >> 1;
    #pragma unroll
    for (int p = 0; p < 4; ++p) {
        float c  = fc[(long)s_idx * 64 + i0 + p];
        float sn = fs[(long)s_idx * 64 + i0 + p];
        float x0 = bf2f(v[2 * p]), x1 = bf2f(v[2 * p + 1]);
        o[2 * p]     = (short)f2bf(x0 * c - x1 * sn);
        o[2 * p + 1] = (short)f2bf(x0 * sn + x1 * c);
    }
    *reinterpret_cast<short8*>(X + base) = o;
}

// ---------------- causal flash attention ----------------
// grid: (S/64, B*H). 256 threads = 4 waves, each wave owns 16 q-rows.
// KV tiles of 32 staged in LDS; online softmax; P via wave-private LDS.
__global__ __launch_bounds__(256) void attn_kernel(const ushort_t* __restrict__ Q,
                                                   const ushort_t* __restrict__ K,
                                                   const ushort_t* __restrict__ V,
                                                   ushort_t* __restrict__ O,
                                                   int S, int H) {
    __shared__ ushort_t Ks[32][136];    // K tile, row-major, padded
    __shared__ ushort_t Vt[128][40];    // V tile transposed [d][kv], padded
    __shared__ ushort_t Pl[4][16][40];  // per-wave P tile [qrow][kv], padded
    const int t = threadIdx.x, wid = t >> 6, lane = t & 63;
    const int lr = lane & 15, lg = lane >> 4;
    const int qb0 = blockIdx.x * 64;
    const int bh = blockIdx.y;
    const long headoff = ((long)(bh / H) * S * H + (bh % H)) * 128;
    const ushort_t* Qh = Q + headoff;
    const ushort_t* Kh = K + headoff;
    const ushort_t* Vh = V + headoff;
    const int rowstride = H * 128;

    // Q fragments: A-operand, row = lane&15, k contiguous per lane-group
    const int qrow = qb0 + wid * 16 + lr;
    short8 qf[4];
    #pragma unroll
    for (int kk = 0; kk < 4; ++kk)
        qf[kk] = *reinterpret_cast<const short8*>(Qh + (long)qrow * rowstride + kk * 32 + lg * 8);

    f32x4 oacc[8] = {};
    float mrow[4], lsum[4];
    #pragma unroll
    for (int r = 0; r < 4; ++r) { mrow[r] = -INFINITY; lsum[r] = 0.f; }

    const int wqmax = qb0 + wid * 16 + 15;
    const int nkt = qb0 / 32 + 2;
    const float scale = 0.08838834764831845f; // 1/sqrt(128)

    const int str = t >> 3;           // staging row 0..31
    const int stc = (t & 7) * 16;     // staging col 0..112

    for (int kt = 0; kt < nkt; ++kt) {
        const int kv0 = kt * 32;
        __syncthreads();
        // stage K tile (row-major)
        const ushort_t* kgp = Kh + (long)(kv0 + str) * rowstride + stc;
        *reinterpret_cast<short8*>(&Ks[str][stc])     = *reinterpret_cast<const short8*>(kgp);
        *reinterpret_cast<short8*>(&Ks[str][stc + 8]) = *reinterpret_cast<const short8*>(kgp + 8);
        // stage V tile transposed
        const ushort_t* vgp = Vh + (long)(kv0 + str) * rowstride + stc;
        short8 v0 = *reinterpret_cast<const short8*>(vgp);
        short8 v1 = *reinterpret_cast<const short8*>(vgp + 8);
        #pragma unroll
        for (int i = 0; i < 8; ++i) {
            Vt[stc + i][str]     = (ushort_t)v0[i];
            Vt[stc + 8 + i][str] = (ushort_t)v1[i];
        }
        __syncthreads();
        if (kv0 > wqmax) continue;   // wave-uniform skip (no barriers inside)

        // QK^T: S-tile 16x32 per wave
        f32x4 sacc[2] = {};
        #pragma unroll
        for (int kk = 0; kk < 4; ++kk) {
            #pragma unroll
            for (int n = 0; n < 2; ++n) {
                short8 kf = *reinterpret_cast<const short8*>(&Ks[n * 16 + lr][kk * 32 + lg * 8]);
                sacc[n] = __builtin_amdgcn_mfma_f32_16x16x32_bf16(qf[kk], kf, sacc[n], 0, 0, 0);
            }
        }
        // scale + causal mask; online softmax
        float sv[2][4];
        const int myq = qb0 + wid * 16 + lg * 4;
        #pragma unroll
        for (int n = 0; n < 2; ++n) {
            int kcol = kv0 + n * 16 + lr;
            #pragma unroll
            for (int r = 0; r < 4; ++r) {
                float xv = sacc[n][r] * scale;
                sv[n][r] = (kcol > myq + r) ? -1e9f : xv;
            }
        }
        float alpha[4];
        #pragma unroll
        for (int r = 0; r < 4; ++r) {
            float mx = fmaxf(sv[0][r], sv[1][r]);
            #pragma unroll
            for (int off = 1; off < 16; off <<= 1)
                mx = fmaxf(mx, __shfl_xor(mx, off));
            float mnew = fmaxf(mrow[r], mx);
            alpha[r] = __expf(mrow[r] - mnew);
            float p0 = __expf(sv[0][r] - mnew);
            float p1 = __expf(sv[1][r] - mnew);
            sv[0][r] = p0; sv[1][r] = p1;
            float ts = p0 + p1;
            #pragma unroll
            for (int off = 1; off < 16; off <<= 1)
                ts += __shfl_xor(ts, off);
            lsum[r] = lsum[r] * alpha[r] + ts;
            mrow[r] = mnew;
        }
        // rescale O
        #pragma unroll
        for (int f = 0; f < 8; ++f)
            #pragma unroll
            for (int r = 0; r < 4; ++r)
                oacc[f][r] *= alpha[r];
        // P -> LDS (wave-private; intra-wave DS ops are in-order)
        #pragma unroll
        for (int n = 0; n < 2; ++n)
            #pragma unroll
            for (int r = 0; r < 4; ++r)
                Pl[wid][lg * 4 + r][n * 16 + lr] = f2bf(sv[n][r]);
        __asm volatile("" ::: "memory");  // no compiler reorder of LDS write->read
        // PV: O-tile 16x128 per wave
        short8 pf = *reinterpret_cast<const short8*>(&Pl[wid][lr][lg * 8]);
        #pragma unroll
        for (int f = 0; f < 8; ++f) {
            short8 vf = *reinterpret_cast<const short8*>(&Vt[f * 16 + lr][lg * 8]);
            oacc[f] = __builtin_amdgcn_mfma_f32_16x16x32_bf16(pf, vf, oacc[f], 0, 0, 0);
        }
    }
    // epilogue: normalize and store bf16 (B,S,H,128)
    float inv[4];
    #pragma unroll
    for (int r = 0; r < 4; ++r) inv[r] = 1.f / lsum[r];
    ushort_t* Oh = O + headoff;
    #pragma unroll
    for (int f = 0; f < 8; ++f) {
        #pragma unroll
        for (int r = 0; r < 4; ++r) {
            int row = qb0 + wid * 16 + lg * 4 + r;
            int col = f * 16 + lr;
            Oh[(long)row * rowstride + col] = f2bf(oacc[f][r] * inv[r]);
        }
    }
}

extern "C" void kernel_launch(void* const* d_in, const int* in_sizes, int n_in,
                              void* d_out, int out_size, void* d_ws, size_t ws_size,
                              hipStream_t stream) {
    const float* x  = (const float*)d_in[0];
    const float* fc = (const float*)d_in[1];
    const float* fs = (const float*)d_in[2];
    const float* wq = (const float*)d_in[3];
    const float* wk = (const float*)d_in[4];
    const float* wv = (const float*)d_in[5];
    const float* wo = (const float*)d_in[6];
    float* out = (float*)d_out;

    const int B = 2, S = 2048, D = 2048, H = 16;
    const int M = B * S;            // 4096
    const size_t MD = (size_t)M * D;
    const size_t DD = (size_t)D * D;

    char* ws = (char*)d_ws;
    ushort_t* xbf = (ushort_t*)ws;                    // M*D bf16 (reused for attn out)
    ushort_t* wqb = (ushort_t*)(ws + MD * 2);
    ushort_t* wkb = wqb + DD;
    ushort_t* wvb = wkb + DD;
    ushort_t* wob = wvb + DD;
    ushort_t* qb  = wob + DD;
    ushort_t* kb  = qb + MD;
    ushort_t* vb  = kb + MD;
    ushort_t* attnb = xbf;                            // reuse (x no longer needed)

    // 1) converts
    cvt_kernel<<<2048, 256, 0, stream>>>(x,  xbf, (int)(MD / 8));
    cvt_kernel<<<2048, 256, 0, stream>>>(wq, wqb, (int)(DD / 8));
    cvt_kernel<<<2048, 256, 0, stream>>>(wk, wkb, (int)(DD / 8));
    cvt_kernel<<<2048, 256, 0, stream>>>(wv, wvb, (int)(DD / 8));
    cvt_kernel<<<2048, 256, 0, stream>>>(wo, wob, (int)(DD / 8));

    // 2) QKV projections
    dim3 gg(D / 128, M / 128);
    gemm_nt<1><<<gg, 256, 0, stream>>>(xbf, wqb, qb, M, D, D);
    gemm_nt<1><<<gg, 256, 0, stream>>>(xbf, wkb, kb, M, D, D);
    gemm_nt<1><<<gg, 256, 0, stream>>>(xbf, wvb, vb, M, D, D);

    // 3) RoPE on Q, K
    const int total8 = (int)(MD / 8);
    rope_kernel<<<(total8 + 255) / 256, 256, 0, stream>>>(qb, fc, fs, total8, H, S);
    rope_kernel<<<(total8 + 255) / 256, 256, 0, stream>>>(kb, fc, fs, total8, H, S);

    // 4) causal flash attention
    dim3 ga(S / 64, B * H);
    attn_kernel<<<ga, 256, 0, stream>>>(qb, kb, vb, attnb, S, H);

    // 5) output projection (fp32 out)
    gemm_nt<0><<<gg, 256, 0, stream>>>(attnb, wob, out, M, D, D);
}

// Round 2
// 379.493 us; speedup vs baseline: 1.6207x; 1.6207x over previous
//
#include <hip/hip_runtime.h>
#include <hip/hip_bf16.h>
#include <math.h>

typedef __attribute__((ext_vector_type(8))) short short8;
typedef __attribute__((ext_vector_type(4))) float f32x4;
typedef unsigned short ushort_t;

__device__ __forceinline__ ushort_t f2bf(float f) {
    union { float f; unsigned u; } v; v.f = f;
    unsigned r = v.u + 0x7FFF + ((v.u >> 16) & 1);
    return (ushort_t)(r >> 16);
}
__device__ __forceinline__ float bf2f(short s) {
    union { unsigned u; float f; } v; v.u = ((unsigned)(ushort_t)s) << 16;
    return v.f;
}

// ---------------- fp32 -> bf16 convert (vectorized x8) ----------------
__global__ void cvt_kernel(const float* __restrict__ src, ushort_t* __restrict__ dst, int n8) {
    int i = blockIdx.x * blockDim.x + threadIdx.x;
    int stride = gridDim.x * blockDim.x;
    for (; i < n8; i += stride) {
        const float4* s = reinterpret_cast<const float4*>(src) + (size_t)i * 2;
        float4 a = s[0], b = s[1];
        short8 o;
        o[0] = (short)f2bf(a.x); o[1] = (short)f2bf(a.y);
        o[2] = (short)f2bf(a.z); o[3] = (short)f2bf(a.w);
        o[4] = (short)f2bf(b.x); o[5] = (short)f2bf(b.y);
        o[6] = (short)f2bf(b.z); o[7] = (short)f2bf(b.w);
        reinterpret_cast<short8*>(dst)[i] = o;
    }
}

// ---------------- GEMM NT (m97 structure): linear LDS + global_load_lds w16 ----------------
// 128x128 tile, BK=32, 256 threads = 4 waves (2x2), each wave 64x64 = 4x4 frags of 16x16x32.
template<int OUT_BF16>
__global__ __launch_bounds__(256) void gemm_nt(const ushort_t* __restrict__ A,
                                               const ushort_t* __restrict__ Bw,
                                               void* __restrict__ Cout,
                                               int M, int N, int K) {
    __shared__ __align__(16) ushort_t As[128 * 32];
    __shared__ __align__(16) ushort_t Bs[128 * 32];
    const int t = threadIdx.x;
    const int wid = t >> 6, lane = t & 63;
    const int wm = wid >> 1, wn = wid & 1;
    const int lr = lane & 15, lg = lane >> 4;
    const int m0 = blockIdx.y * 128, n0 = blockIdx.x * 128;

    f32x4 acc[4][4] = {};

    // staging: wave w stages shorts [w*1024, w*1024+1024) in 2 issues of 1KB
    const int sh0 = wid * 1024 + lane * 8;        // element index, issue 0
    const int sh1 = sh0 + 512;                    // issue 1
    const int r0 = sh0 >> 5, c0 = sh0 & 31;
    const int r1 = sh1 >> 5, c1 = sh1 & 31;

    const ushort_t* gA0 = A + (long)(m0 + r0) * K + c0;
    const ushort_t* gA1 = A + (long)(m0 + r1) * K + c1;
    const ushort_t* gB0 = Bw + (long)(n0 + r0) * K + c0;
    const ushort_t* gB1 = Bw + (long)(n0 + r1) * K + c1;

    for (int k0 = 0; k0 < K; k0 += 32) {
        __syncthreads();
        __builtin_amdgcn_global_load_lds((const __attribute__((address_space(1))) unsigned int*)(gA0 + k0),
                                         (__attribute__((address_space(3))) unsigned int*)(As + sh0), 16, 0, 0);
        __builtin_amdgcn_global_load_lds((const __attribute__((address_space(1))) unsigned int*)(gA1 + k0),
                                         (__attribute__((address_space(3))) unsigned int*)(As + sh1), 16, 0, 0);
        __builtin_amdgcn_global_load_lds((const __attribute__((address_space(1))) unsigned int*)(gB0 + k0),
                                         (__attribute__((address_space(3))) unsigned int*)(Bs + sh0), 16, 0, 0);
        __builtin_amdgcn_global_load_lds((const __attribute__((address_space(1))) unsigned int*)(gB1 + k0),
                                         (__attribute__((address_space(3))) unsigned int*)(Bs + sh1), 16, 0, 0);
        __syncthreads();
        short8 af[4], bfr[4];
        #pragma unroll
        for (int m = 0; m < 4; ++m)
            af[m] = *reinterpret_cast<const short8*>(&As[(wm * 64 + m * 16 + lr) * 32 + lg * 8]);
        #pragma unroll
        for (int n = 0; n < 4; ++n)
            bfr[n] = *reinterpret_cast<const short8*>(&Bs[(wn * 64 + n * 16 + lr) * 32 + lg * 8]);
        #pragma unroll
        for (int m = 0; m < 4; ++m)
            #pragma unroll
            for (int n = 0; n < 4; ++n)
                acc[m][n] = __builtin_amdgcn_mfma_f32_16x16x32_bf16(af[m], bfr[n], acc[m][n], 0, 0, 0);
    }
    // epilogue: C/D layout col = lane&15, row = (lane>>4)*4 + r  [m89-verified]
    #pragma unroll
    for (int m = 0; m < 4; ++m) {
        #pragma unroll
        for (int n = 0; n < 4; ++n) {
            #pragma unroll
            for (int r = 0; r < 4; ++r) {
                int row = m0 + wm * 64 + m * 16 + lg * 4 + r;
                int col = n0 + wn * 64 + n * 16 + lr;
                float v = acc[m][n][r];
                if (OUT_BF16)
                    ((ushort_t*)Cout)[(long)row * N + col] = f2bf(v);
                else
                    ((float*)Cout)[(long)row * N + col] = v;
            }
        }
    }
}

// ---------------- RoPE (interleaved pairs), in-place on (B,S,H,128) bf16 ----------------
__global__ void rope_kernel(ushort_t* __restrict__ X, const float* __restrict__ fc,
                            const float* __restrict__ fs, int total8, int H, int S) {
    int i = blockIdx.x * blockDim.x + threadIdx.x;
    if (i >= total8) return;
    const long base = (long)i * 8;
    const int d = (int)(base & 127);
    const long row = base >> 7;
    const int s_idx = (int)((row / H) % S);
    short8 v = *reinterpret_cast<const short8*>(X + base);
    short8 o;
    const int i0 = d >> 1;
    #pragma unroll
    for (int p = 0; p < 4; ++p) {
        float c  = fc[(long)s_idx * 64 + i0 + p];
        float sn = fs[(long)s_idx * 64 + i0 + p];
        float x0 = bf2f(v[2 * p]), x1 = bf2f(v[2 * p + 1]);
        o[2 * p]     = (short)f2bf(x0 * c - x1 * sn);
        o[2 * p + 1] = (short)f2bf(x0 * sn + x1 * c);
    }
    *reinterpret_cast<short8*>(X + base) = o;
}

// ---------------- V transpose in global: V[B,S,H,hd] -> Vt[B*H, hd, S] ----------------
// grid (S/16, B*H), block 256: t -> d = t&127, sc = t>>7. Coalesced reads (256B/row),
// scattered 16B writes (once per element, vs per-q-block LDS transposes).
__global__ void vtrans_kernel(const ushort_t* __restrict__ V, ushort_t* __restrict__ Vt,
                              int S, int H) {
    const int bh = blockIdx.y;
    const int s0 = blockIdx.x * 16 + ((threadIdx.x >> 7) * 8);
    const int d = threadIdx.x & 127;
    const long vbase = ((long)(bh / H) * S * H + (bh % H)) * 128;
    const int rowstride = H * 128;
    short8 o;
    #pragma unroll
    for (int i = 0; i < 8; ++i)
        o[i] = (short)V[vbase + (long)(s0 + i) * rowstride + d];
    *reinterpret_cast<short8*>(Vt + ((long)bh * 128 + d) * S + s0) = o;
}

// ---------------- causal flash attention (KVB=64, folded q-tiles) ----------------
// grid: (S/64/2, B*H). 256 threads = 4 waves, each wave owns 16 q-rows.
// Block bx processes q-tiles bx and (nq-1-bx): uniform 33 kv-tiles per block.
__global__ __launch_bounds__(256) void attn_kernel(const ushort_t* __restrict__ Q,
                                                   const ushort_t* __restrict__ K,
                                                   const ushort_t* __restrict__ Vtg,
                                                   ushort_t* __restrict__ O,
                                                   int S, int H) {
    __shared__ __align__(16) ushort_t Ks[64][136];   // K tile row-major [kv][d], padded
    __shared__ __align__(16) ushort_t Vs[128][72];   // V^T tile [d][kv], padded
    __shared__ __align__(16) ushort_t Pl[4][16][72]; // per-wave P [qrow][kv], padded
    const int t = threadIdx.x, wid = t >> 6, lane = t & 63;
    const int lr = lane & 15, lg = lane >> 4;
    const int bh = blockIdx.y;
    const long headoff = ((long)(bh / H) * S * H + (bh % H)) * 128;
    const ushort_t* Qh = Q + headoff;
    const ushort_t* Kh = K + headoff;
    const ushort_t* Vth = Vtg + (long)bh * 128 * S;
    const int rowstride = H * 128;
    const int nq = S / 64;
    const float scale = 0.08838834764831845f; // 1/sqrt(128)

    // staging maps
    const int ksr = t >> 2;          // K stage row 0..63
    const int ksc = (t & 3) * 32;    // K stage col base
    const int vsr = t & 127;         // V stage row (d) 0..127
    const int vsc = (t >> 7) * 32;   // V stage col base

    for (int qsel = 0; qsel < 2; ++qsel) {
        const int qt = qsel ? (nq - 1 - blockIdx.x) : blockIdx.x;
        const int qb0 = qt * 64;

        const int qrow = qb0 + wid * 16 + lr;
        short8 qf[4];
        #pragma unroll
        for (int kk = 0; kk < 4; ++kk)
            qf[kk] = *reinterpret_cast<const short8*>(Qh + (long)qrow * rowstride + kk * 32 + lg * 8);

        f32x4 oacc[8] = {};
        float mrow[4], lsum[4];
        #pragma unroll
        for (int r = 0; r < 4; ++r) { mrow[r] = -INFINITY; lsum[r] = 0.f; }

        const int nkt = qt + 1;
        for (int kt = 0; kt < nkt; ++kt) {
            const int kv0 = kt * 64;
            __syncthreads();
            // stage K (vector writes)
            const ushort_t* kgp = Kh + (long)(kv0 + ksr) * rowstride + ksc;
            #pragma unroll
            for (int j = 0; j < 4; ++j)
                *reinterpret_cast<short8*>(&Ks[ksr][ksc + j * 8]) = *reinterpret_cast<const short8*>(kgp + j * 8);
            // stage V^T rows (vector writes, from pre-transposed global)
            const ushort_t* vgp = Vth + (long)vsr * S + kv0 + vsc;
            #pragma unroll
            for (int j = 0; j < 4; ++j)
                *reinterpret_cast<short8*>(&Vs[vsr][vsc + j * 8]) = *reinterpret_cast<const short8*>(vgp + j * 8);
            __syncthreads();

            // QK^T: S-tile 16x64 per wave
            f32x4 sacc[4] = {};
            #pragma unroll
            for (int kk = 0; kk < 4; ++kk) {
                #pragma unroll
                for (int n = 0; n < 4; ++n) {
                    short8 kf = *reinterpret_cast<const short8*>(&Ks[n * 16 + lr][kk * 32 + lg * 8]);
                    sacc[n] = __builtin_amdgcn_mfma_f32_16x16x32_bf16(qf[kk], kf, sacc[n], 0, 0, 0);
                }
            }
            // scale + causal mask + online softmax
            float sv[4][4];
            const int myq = qb0 + wid * 16 + lg * 4;
            #pragma unroll
            for (int n = 0; n < 4; ++n) {
                int kcol = kv0 + n * 16 + lr;
                #pragma unroll
                for (int r = 0; r < 4; ++r) {
                    float xv = sacc[n][r] * scale;
                    sv[n][r] = (kcol > myq + r) ? -1e9f : xv;
                }
            }
            float alpha[4];
            #pragma unroll
            for (int r = 0; r < 4; ++r) {
                float mx = fmaxf(fmaxf(sv[0][r], sv[1][r]), fmaxf(sv[2][r], sv[3][r]));
                #pragma unroll
                for (int off = 1; off < 16; off <<= 1)
                    mx = fmaxf(mx, __shfl_xor(mx, off));
                float mnew = fmaxf(mrow[r], mx);
                alpha[r] = __expf(mrow[r] - mnew);
                float ts = 0.f;
                #pragma unroll
                for (int n = 0; n < 4; ++n) {
                    float p = __expf(sv[n][r] - mnew);
                    sv[n][r] = p;
                    ts += p;
                }
                #pragma unroll
                for (int off = 1; off < 16; off <<= 1)
                    ts += __shfl_xor(ts, off);
                lsum[r] = lsum[r] * alpha[r] + ts;
                mrow[r] = mnew;
            }
            #pragma unroll
            for (int f = 0; f < 8; ++f)
                #pragma unroll
                for (int r = 0; r < 4; ++r)
                    oacc[f][r] *= alpha[r];
            // P -> wave-private LDS
            #pragma unroll
            for (int n = 0; n < 4; ++n)
                #pragma unroll
                for (int r = 0; r < 4; ++r)
                    Pl[wid][lg * 4 + r][n * 16 + lr] = f2bf(sv[n][r]);
            __asm volatile("" ::: "memory");
            short8 pf[2];
            #pragma unroll
            for (int ks = 0; ks < 2; ++ks)
                pf[ks] = *reinterpret_cast<const short8*>(&Pl[wid][lr][ks * 32 + lg * 8]);
            // PV: O-tile 16x128 per wave
            #pragma unroll
            for (int f = 0; f < 8; ++f) {
                #pragma unroll
                for (int ks = 0; ks < 2; ++ks) {
                    short8 vf = *reinterpret_cast<const short8*>(&Vs[f * 16 + lr][ks * 32 + lg * 8]);
                    oacc[f] = __builtin_amdgcn_mfma_f32_16x16x32_bf16(pf[ks], vf, oacc[f], 0, 0, 0);
                }
            }
        }
        // epilogue
        float inv[4];
        #pragma unroll
        for (int r = 0; r < 4; ++r) inv[r] = 1.f / lsum[r];
        ushort_t* Oh = O + headoff;
        #pragma unroll
        for (int f = 0; f < 8; ++f) {
            #pragma unroll
            for (int r = 0; r < 4; ++r) {
                int row = qb0 + wid * 16 + lg * 4 + r;
                int col = f * 16 + lr;
                Oh[(long)row * rowstride + col] = f2bf(oacc[f][r] * inv[r]);
            }
        }
    }
}

extern "C" void kernel_launch(void* const* d_in, const int* in_sizes, int n_in,
                              void* d_out, int out_size, void* d_ws, size_t ws_size,
                              hipStream_t stream) {
    const float* x  = (const float*)d_in[0];
    const float* fc = (const float*)d_in[1];
    const float* fs = (const float*)d_in[2];
    const float* wq = (const float*)d_in[3];
    const float* wk = (const float*)d_in[4];
    const float* wv = (const float*)d_in[5];
    const float* wo = (const float*)d_in[6];
    float* out = (float*)d_out;

    const int B = 2, S = 2048, D = 2048, H = 16;
    const int M = B * S;            // 4096
    const size_t MD = (size_t)M * D;
    const size_t DD = (size_t)D * D;

    char* ws = (char*)d_ws;
    ushort_t* xbf = (ushort_t*)ws;                    // M*D bf16 (reused for attn out)
    ushort_t* wqb = (ushort_t*)(ws + MD * 2);
    ushort_t* wkb = wqb + DD;
    ushort_t* wvb = wkb + DD;
    ushort_t* wob = wvb + DD;
    ushort_t* qb  = wob + DD;
    ushort_t* kb  = qb + MD;
    ushort_t* vb  = kb + MD;
    ushort_t* attnb = xbf;        // reuse (x dead after QKV GEMMs)
    ushort_t* vtg   = wqb;        // reuse wq/wk/wv bf16 region (dead after QKV GEMMs); 16.8MB fits in 25.2MB

    // 1) converts
    cvt_kernel<<<2048, 256, 0, stream>>>(x,  xbf, (int)(MD / 8));
    cvt_kernel<<<2048, 256, 0, stream>>>(wq, wqb, (int)(DD / 8));
    cvt_kernel<<<2048, 256, 0, stream>>>(wk, wkb, (int)(DD / 8));
    cvt_kernel<<<2048, 256, 0, stream>>>(wv, wvb, (int)(DD / 8));
    cvt_kernel<<<2048, 256, 0, stream>>>(wo, wob, (int)(DD / 8));

    // 2) QKV projections
    dim3 gg(D / 128, M / 128);
    gemm_nt<1><<<gg, 256, 0, stream>>>(xbf, wqb, qb, M, D, D);
    gemm_nt<1><<<gg, 256, 0, stream>>>(xbf, wkb, kb, M, D, D);
    gemm_nt<1><<<gg, 256, 0, stream>>>(xbf, wvb, vb, M, D, D);

    // 3) RoPE on Q, K
    const int total8 = (int)(MD / 8);
    rope_kernel<<<(total8 + 255) / 256, 256, 0, stream>>>(qb, fc, fs, total8, H, S);
    rope_kernel<<<(total8 + 255) / 256, 256, 0, stream>>>(kb, fc, fs, total8, H, S);

    // 4) V transpose (global, once) then causal flash attention
    dim3 gv(S / 16, B * H);
    vtrans_kernel<<<gv, 256, 0, stream>>>(vb, vtg, S, H);
    dim3 ga(S / 64 / 2, B * H);
    attn_kernel<<<ga, 256, 0, stream>>>(qb, kb, vtg, attnb, S, H);

    // 5) output projection (fp32 out)
    gemm_nt<0><<<gg, 256, 0, stream>>>(attnb, wob, out, M, D, D);
}